// Round 10
// baseline (93.444 us; speedup 1.0000x reference)
//
#include <hip/hip_runtime.h>
#include <hip/hip_fp16.h>

typedef _Float16 f16x8 __attribute__((ext_vector_type(8)));
typedef float f32x4 __attribute__((ext_vector_type(4)));
typedef unsigned int uint32;

#define LDW 136   // row stride in halves (272B: 16B-aligned)
#define TB  16    // tokens per block

// wait only lgkmcnt(0): vmcnt=63, expcnt=7, lgkmcnt=0 -> 0xC07F
#define WAITLGKM() do { __builtin_amdgcn_s_waitcnt(0xC07F); __builtin_amdgcn_sched_barrier(0); } while(0)

// lgkm-only barrier: leaves global (VGPR-destined) prefetches in flight.
#define BAR() do {                                          \
  asm volatile("s_waitcnt lgkmcnt(0)" ::: "memory");        \
  __builtin_amdgcn_sched_barrier(0);                        \
  __builtin_amdgcn_s_barrier();                             \
  __builtin_amdgcn_sched_barrier(0);                        \
} while (0)

union F16x8U { f16x8 v; __half2 h2[4]; uint2 u2[2]; uint4 u4; };

__device__ __forceinline__ uint32 pk2f(float a, float b) {
  __half2 h = __floats2half2_rn(a, b);
  return *reinterpret_cast<uint32*>(&h);
}
__device__ __forceinline__ float bcast(float v, int sl) {
  return __int_as_float(__builtin_amdgcn_readlane(__float_as_int(v), sl));
}
template <int CTRL, int RMASK = 0xF, int BMASK = 0xF>
__device__ __forceinline__ float dppmov(float v) {
  return __int_as_float(__builtin_amdgcn_update_dpp(
      0, __float_as_int(v), CTRL, RMASK, BMASK, true));
}
template <int PAT>
__device__ __forceinline__ float swzf(float v) {
  return __int_as_float(__builtin_amdgcn_ds_swizzle(__float_as_int(v), PAT));
}
// 64-lane sum via DPP (rocPRIM pattern) -> total broadcast via readlane(63)
__device__ __forceinline__ float wred_sum(float v) {
  v += dppmov<0x111>(v);                      // row_shr:1
  v += dppmov<0x112>(v);                      // row_shr:2
  v += dppmov<0x114>(v);                      // row_shr:4
  v += dppmov<0x118>(v);                      // row_shr:8
  v += dppmov<0x142, 0xA>(v);                 // row_bcast:15 (rows 1,3)
  v += dppmov<0x143, 0xC>(v);                 // row_bcast:31 (rows 2,3)
  return __int_as_float(__builtin_amdgcn_readlane(__float_as_int(v), 63));
}
__device__ __forceinline__ f16x8 ldsv8(const __half* p) {
  return *reinterpret_cast<const f16x8*>(p);   // ds_read_b128
}
__device__ __forceinline__ f32x4 mfma16(f16x8 a, f16x8 b, f32x4 c) {
  return __builtin_amdgcn_mfma_f32_16x16x32_f16(a, b, c, 0, 0, 0);
}
// packed C-frag store: C[m][n=fr] -> row-major act[tok=fr][c], 1x ds_write_b64
__device__ __forceinline__ void stp(__half* base, int fr, int fq, int nt, f32x4 a) {
  uint2 u; u.x = pk2f(a[0], a[1]); u.y = pk2f(a[2], a[3]);
  *reinterpret_cast<uint2*>(&base[fr * LDW + nt * 16 + fq * 4]) = u;
}

// ---- workspace layout (halves) ----
// Wqk[h][i][c]  : qw = x @ Wqk (P1+P2 fused). WqkT layout [h][i(c_out) 128][c(k) 128]
// WvmT[c'][k512]: y = ctx @ Wvm (P4+P5 fused). k = h*128 + i
#define OFF_WQK  0
#define OFF_WVM  65536
#define OFF_W1   131072
#define OFF_W2   147456
#define WS_HALVES 163840

__global__ void prep_weights(const float* __restrict__ wq, const float* __restrict__ wkv,
                             const float* __restrict__ wmh, const float* __restrict__ w1,
                             const float* __restrict__ w2, __half* __restrict__ ws) {
  int idx = blockIdx.x * 256 + threadIdx.x;
  if (idx >= WS_HALVES) return;
  float v;
  if (idx < OFF_WVM) {            // WqkT[h][i][c] = sum_d wq[c][h*32+d]*wkv[i][h*32+d]
    int h = idx >> 14, r = idx & 16383, i = r >> 7, c = r & 127;
    const float* wqp = wq + c * 128 + h * 32;
    const float* wkp = wkv + i * 256 + h * 32;
    float acc = 0.f;
#pragma unroll 8
    for (int d = 0; d < 32; ++d) acc = fmaf(wqp[d], wkp[d], acc);
    v = acc;
  } else if (idx < OFF_W1) {      // WvmT[c'][h*128+i] = sum_d wkv[i][128+h*32+d]*wmh[h*32+d][c']
    int t = idx - OFF_WVM;
    int cp = t >> 9, k = t & 511, h = k >> 7, i = k & 127;
    const float* wvp = wkv + i * 256 + 128 + h * 32;
    const float* wmp = wmh + (h * 32) * 128 + cp;
    float acc = 0.f;
#pragma unroll 8
    for (int d = 0; d < 32; ++d) acc = fmaf(wvp[d], wmp[d * 128], acc);
    v = acc;
  } else if (idx < OFF_W2) {      // w1T [c_out][k]
    int t = idx - OFF_W1, c = t >> 7, k = t & 127;
    v = w1[k * 128 + c];
  } else {                        // w2T
    int t = idx - OFF_W2, c = t >> 7, k = t & 127;
    v = w2[k * 128 + c];
  }
  ws[idx] = __float2half_rn(v);
}

// load W frags (2 c_out-tiles x 4 k-slices) of a [128][128] c-major matrix (A operand)
#define LOADB2(GOFF, NT0, NT1, BF) do {                                          \
  _Pragma("unroll")                                                              \
  for (int t_ = 0; t_ < 2; ++t_) {                                               \
    int nt_ = t_ ? (NT1) : (NT0);                                                \
    _Pragma("unroll")                                                            \
    for (int ks_ = 0; ks_ < 4; ++ks_)                                            \
      BF[t_][ks_] = *reinterpret_cast<const f16x8*>(                             \
          wsv + (GOFF) + (nt_*16 + fr)*128 + ks_*32 + fq*8);                     \
  } } while (0)

// two 16x16 tiles: A = weights (BF), B = activation tile (row-major [tok][c])
#define GEMM2(AT, BF, ACC0, ACC1) do {                                           \
  _Pragma("unroll")                                                              \
  for (int ks_ = 0; ks_ < 4; ++ks_) {                                            \
    f16x8 b_ = ldsv8(&(AT)[fr * LDW + ks_ * 32 + fq * 8]);                       \
    ACC0 = mfma16(BF[0][ks_], b_, ACC0);                                         \
    ACC1 = mfma16(BF[1][ks_], b_, ACC1);                                         \
  } } while (0)

__global__ void __launch_bounds__(256, 6) ca_mfma(
    const float* __restrict__ xq, const float* __restrict__ kvin,
    const __half* __restrict__ wsv,
    const float* __restrict__ bmh, const float* __restrict__ b1,
    const float* __restrict__ b2,
    const float* __restrict__ g1, const float* __restrict__ bb1,
    const float* __restrict__ g2, const float* __restrict__ bb2,
    float* __restrict__ outp)
{
  // LDS: 17408 + 8704 = 26112 B -> 6 blocks/CU
  __shared__ __half QWC[64 * LDW];      // qw/ctx rows [h*16+tok]; later Hb(0-15), Vb(16-31)
  __shared__ __half UBUF[2 * TB * LDW]; // Xh(0-15) -> kvw(per wave) -> Yb(0-15), RESb(16-31)

  const int tid = threadIdx.x;
  const int wv = tid >> 6, lane = tid & 63;
  const int fr = lane & 15, fq = lane >> 4;   // MFMA frag row / k-group
  const int tb = blockIdx.x * TB;
  const int ltb = wv * 4;

  __half* Xh   = UBUF;              // rows 0-15 (dead after F1)
  __half* Yb   = UBUF;              // rows 0-15 (written F2; kvw wv0/1 dead)
  __half* RESb = UBUF + 16 * LDW;   // rows 16-31 (kvw wv2/3 dead)
  __half* Hb   = QWC;               // rows 0-15 (ctx dead after F2)
  __half* Vb   = QWC + 16 * LDW;    // rows 16-31

  const f32x4 ZZ = {0.f, 0.f, 0.f, 0.f};

  // ---- Xh stage (f16, row-major [tok][c], stride LDW) ----
  {
    int tok = tid >> 4, ko = (tid & 15) * 8;
    const float4* s0 = reinterpret_cast<const float4*>(xq + (size_t)(tb + tok) * 128 + ko);
    float4 a = s0[0], b = s0[1];
    uint4 u; u.x = pk2f(a.x, a.y); u.y = pk2f(a.z, a.w);
    u.z = pk2f(b.x, b.y); u.w = pk2f(b.z, b.w);
    *reinterpret_cast<uint4*>(&Xh[tok * LDW + ko]) = u;
  }
  BAR();  // 1: Xh ready

  // ---- F1 (P1+P2 fused): qw[h=wv][tok][i] = x @ Wqk[wv] -> QWC rows wv*16+tok ----
  {
    f16x8 bx[4];
#pragma unroll
    for (int ks = 0; ks < 4; ++ks) bx[ks] = ldsv8(&Xh[fr * LDW + ks * 32 + fq * 8]);
    const __half* wqk = wsv + OFF_WQK + wv * 16384 + fr * 128 + fq * 8;
#pragma unroll
    for (int t = 0; t < 4; ++t) {
      f16x8 a0[4], a1[4];
#pragma unroll
      for (int ks = 0; ks < 4; ++ks) {
        a0[ks] = *reinterpret_cast<const f16x8*>(wqk + (2 * t) * 2048 + ks * 32);
        a1[ks] = *reinterpret_cast<const f16x8*>(wqk + (2 * t + 1) * 2048 + ks * 32);
      }
      f32x4 q0 = ZZ, q1 = ZZ;
#pragma unroll
      for (int ks = 0; ks < 4; ++ks) {
        q0 = mfma16(a0[ks], bx[ks], q0);
        q1 = mfma16(a1[ks], bx[ks], q1);
      }
      stp(QWC + wv * 16 * LDW, fr, fq, 2 * t, q0);
      stp(QWC + wv * 16 * LDW, fr, fq, 2 * t + 1, q1);
    }
  }
  // prefetch this wave's token-0 kv (lands during BAR/P3 start)
  float4 pre[4];
  {
    const float4* kv4 = reinterpret_cast<const float4*>(kvin + (size_t)(tb + ltb) * 1024);
    pre[0] = kv4[2 * lane];       pre[1] = kv4[2 * lane + 1];
    pre[2] = kv4[2 * lane + 128]; pre[3] = kv4[2 * lane + 129];
  }
  BAR();  // 2: qw ready (all heads); Xh dead (kvw may overwrite)

  // ---- P3: wave-local attention, MFMA sim + DPP softmax (unchanged from R9) ----
  {
    const int kr = lane >> 4, i8 = (lane & 15) * 8;
    const int l2 = 2 * lane;
    const float SCALE = 0.17677669529663687f;  // 1/sqrt(32)
    __half* kvw = UBUF + wv * 1088;   // [8][LDW] per wave
#pragma unroll 1
    for (int lt = 0; lt < 4; ++lt) {
      const int ltok = ltb + lt;
      WAITLGKM();   // prior iter's ds_reads of kvw done (WAR)
      {
        uint4 u0, u1;
        u0.x = pk2f(pre[0].x, pre[0].y); u0.y = pk2f(pre[0].z, pre[0].w);
        u0.z = pk2f(pre[1].x, pre[1].y); u0.w = pk2f(pre[1].z, pre[1].w);
        u1.x = pk2f(pre[2].x, pre[2].y); u1.y = pk2f(pre[2].z, pre[2].w);
        u1.z = pk2f(pre[3].x, pre[3].y); u1.w = pk2f(pre[3].z, pre[3].w);
        *reinterpret_cast<uint4*>(&kvw[kr * LDW + i8]) = u0;        // rows 0..3
        *reinterpret_cast<uint4*>(&kvw[(4 + kr) * LDW + i8]) = u1;  // rows 4..7
      }
      if (lt < 3) {
        const float4* kv4 = reinterpret_cast<const float4*>(kvin + (size_t)(tb + ltok + 1) * 1024);
        pre[0] = kv4[2 * lane];       pre[1] = kv4[2 * lane + 1];
        pre[2] = kv4[2 * lane + 128]; pre[3] = kv4[2 * lane + 129];
      }
      WAITLGKM();   // kv writes visible within wave
      // sim via MFMA: A = qw rows (h = fr&3), B = kv rows (k = fr&7)
      f32x4 acc = ZZ;
#pragma unroll
      for (int ks = 0; ks < 4; ++ks) {
        f16x8 a_ = ldsv8(&QWC[((fr & 3) * 16 + ltok) * LDW + ks * 32 + fq * 8]);
        f16x8 b_ = ldsv8(&kvw[(fr & 7) * LDW + ks * 32 + fq * 8]);
        acc = mfma16(a_, b_, acc);
      }
      // softmax over k (8 lanes): quad_perm DPP + ds_swizzle xor4
      float at_[4];
#pragma unroll
      for (int r = 0; r < 4; ++r) {
        float s = acc[r] * SCALE;
        float mx = fmaxf(s, dppmov<0xB1>(s));
        mx = fmaxf(mx, dppmov<0x4E>(mx));
        mx = fmaxf(mx, swzf<0x101F>(mx));
        float e = __expf(s - mx);
        float dn = e + dppmov<0xB1>(e);
        dn += dppmov<0x4E>(dn);
        dn += swzf<0x101F>(dn);
        at_[r] = __fdividef(e, dn);                // lane k holds attn[h=r][k]
      }
      // ctx[h][c] = sum_k at*kv ; lane owns cols 2*lane, 2*lane+1
      __half2 kvc[8];
#pragma unroll
      for (int k = 0; k < 8; ++k)
        kvc[k] = *reinterpret_cast<const __half2*>(&kvw[k * LDW + l2]);
#pragma unroll
      for (int h = 0; h < 4; ++h) {
        float c0 = 0.f, c1 = 0.f;
#pragma unroll
        for (int k = 0; k < 8; ++k) {
          float a = bcast(at_[h], k);
          float2 kf = __half22float2(kvc[k]);
          c0 = fmaf(a, kf.x, c0);
          c1 = fmaf(a, kf.y, c1);
        }
        *reinterpret_cast<__half2*>(&QWC[(h * 16 + ltok) * LDW + l2]) =
            __floats2half2_rn(c0, c1);
      }
    }
  }
  BAR();  // 3: ctx ready; kvw dead

  // ---- F2 (P4+P5 fused): y[tok][c'] = ctx @ Wvm (K=512) -> Yb (UBUF rows 0-15) ----
  float2 xr[4];   // residual x for LN1
#pragma unroll
  for (int lt = 0; lt < 4; ++lt) {
    int tok = tb + ltb + lt;
    xr[lt] = *reinterpret_cast<const float2*>(&xq[(size_t)tok * 128 + 2 * lane]);
  }
  {
    const __half* wvmA = wsv + OFF_WVM + (size_t)(wv * 16 + fr) * 512 + fq * 8;
    const __half* wvmB = wsv + OFF_WVM + (size_t)((4 + wv) * 16 + fr) * 512 + fq * 8;
    f32x4 yA = ZZ, yB = ZZ;
#pragma unroll
    for (int t = 0; t < 4; ++t) {     // t = head (kk = 4t+j)
      f16x8 a0[4], a1[4], b[4];
#pragma unroll
      for (int j = 0; j < 4; ++j) {
        int kk = 4 * t + j;
        a0[j] = *reinterpret_cast<const f16x8*>(wvmA + kk * 32);
        a1[j] = *reinterpret_cast<const f16x8*>(wvmB + kk * 32);
        b[j]  = ldsv8(&QWC[(t * 16 + fr) * LDW + j * 32 + fq * 8]);
      }
#pragma unroll
      for (int j = 0; j < 4; ++j) {
        yA = mfma16(a0[j], b[j], yA);
        yB = mfma16(a1[j], b[j], yB);
      }
    }
    stp(Yb, fr, fq, wv, yA);
    stp(Yb, fr, fq, 4 + wv, yB);
  }
  BAR();  // 4: Yb ready; ctx dead

  // ---- LN1 + residual -> RESb (DPP reductions) ----
  f16x8 bf[2][4];
  {
    const int l2 = 2 * lane;
    float2 bm = *reinterpret_cast<const float2*>(&bmh[l2]);
    float2 gg = *reinterpret_cast<const float2*>(&g1[l2]);
    float2 cc = *reinterpret_cast<const float2*>(&bb1[l2]);
#pragma unroll
    for (int lt = 0; lt < 4; ++lt) {
      int row = ltb + lt;
      float2 y = __half22float2(*reinterpret_cast<const __half2*>(&Yb[row * LDW + l2]));
      float v0 = y.x + bm.x, v1 = y.y + bm.y;
      float s = wred_sum(v0 + v1);
      float sq = wred_sum(v0 * v0 + v1 * v1);
      float mu = s * 0.0078125f;
      float var = sq * 0.0078125f - mu * mu;
      float rstd = rsqrtf(var + 1e-5f);
      float r0 = (v0 - mu) * rstd * gg.x + cc.x + xr[lt].x;
      float r1 = (v1 - mu) * rstd * gg.y + cc.y + xr[lt].y;
      *reinterpret_cast<__half2*>(&RESb[row * LDW + l2]) = __floats2half2_rn(r0, r1);
    }
  }
  LOADB2(OFF_W1, wv, 4 + wv, bf);
  BAR();  // 5: RESb ready; bf(w1) stays in flight

  // ---- P6: h = gelu(W1(A) @ res(B) + b1) -> Hb (QWC rows 0-15) ----
  {
    f32x4 aA = ZZ, aB = ZZ;
    GEMM2(RESb, bf, aA, aB);
    int c0 = wv * 16 + fq * 4, c1 = 64 + wv * 16 + fq * 4;
    float4 b1a = *reinterpret_cast<const float4*>(&b1[c0]);
    float4 b1b = *reinterpret_cast<const float4*>(&b1[c1]);
    uint2 ua, ub;
    float t0, t1;
    t0 = aA[0] + b1a.x; t0 = 0.5f * t0 * (1.f + erff(t0 * 0.70710678118654752f));
    t1 = aA[1] + b1a.y; t1 = 0.5f * t1 * (1.f + erff(t1 * 0.70710678118654752f));
    ua.x = pk2f(t0, t1);
    t0 = aA[2] + b1a.z; t0 = 0.5f * t0 * (1.f + erff(t0 * 0.70710678118654752f));
    t1 = aA[3] + b1a.w; t1 = 0.5f * t1 * (1.f + erff(t1 * 0.70710678118654752f));
    ua.y = pk2f(t0, t1);
    t0 = aB[0] + b1b.x; t0 = 0.5f * t0 * (1.f + erff(t0 * 0.70710678118654752f));
    t1 = aB[1] + b1b.y; t1 = 0.5f * t1 * (1.f + erff(t1 * 0.70710678118654752f));
    ub.x = pk2f(t0, t1);
    t0 = aB[2] + b1b.z; t0 = 0.5f * t0 * (1.f + erff(t0 * 0.70710678118654752f));
    t1 = aB[3] + b1b.w; t1 = 0.5f * t1 * (1.f + erff(t1 * 0.70710678118654752f));
    ub.y = pk2f(t0, t1);
    *reinterpret_cast<uint2*>(&Hb[fr * LDW + c0]) = ua;
    *reinterpret_cast<uint2*>(&Hb[fr * LDW + c1]) = ub;
  }
  LOADB2(OFF_W2, wv, 4 + wv, bf);
  BAR();  // 6: Hb ready; bf(w2) stays in flight

  // ---- P7: v = W2(A) @ h(B) + b2 + res -> Vb (QWC rows 16-31) ----
  {
    f32x4 aA = ZZ, aB = ZZ;
    GEMM2(Hb, bf, aA, aB);
    int c0 = wv * 16 + fq * 4, c1 = 64 + wv * 16 + fq * 4;
    float4 b2a = *reinterpret_cast<const float4*>(&b2[c0]);
    float4 b2b = *reinterpret_cast<const float4*>(&b2[c1]);
    F16x8U ra, rb;
    ra.u2[0] = *reinterpret_cast<const uint2*>(&RESb[fr * LDW + c0]);
    rb.u2[0] = *reinterpret_cast<const uint2*>(&RESb[fr * LDW + c1]);
    uint2 ua, ub;
    float2 p0 = __half22float2(ra.h2[0]), p1 = __half22float2(ra.h2[1]);
    ua.x = pk2f(aA[0] + b2a.x + p0.x, aA[1] + b2a.y + p0.y);
    ua.y = pk2f(aA[2] + b2a.z + p1.x, aA[3] + b2a.w + p1.y);
    float2 p2 = __half22float2(rb.h2[0]), p3 = __half22float2(rb.h2[1]);
    ub.x = pk2f(aB[0] + b2b.x + p2.x, aB[1] + b2b.y + p2.y);
    ub.y = pk2f(aB[2] + b2b.z + p3.x, aB[3] + b2b.w + p3.y);
    *reinterpret_cast<uint2*>(&Vb[fr * LDW + c0]) = ua;
    *reinterpret_cast<uint2*>(&Vb[fr * LDW + c1]) = ub;
  }
  BAR();  // 7: Vb ready

  // ---- LN2 + store (DPP reductions) ----
  {
    const int l2 = 2 * lane;
    float2 gg = *reinterpret_cast<const float2*>(&g2[l2]);
    float2 cc = *reinterpret_cast<const float2*>(&bb2[l2]);
#pragma unroll
    for (int lt = 0; lt < 4; ++lt) {
      int row = ltb + lt, tok = tb + row;
      float2 v = __half22float2(*reinterpret_cast<const __half2*>(&Vb[row * LDW + l2]));
      float s = wred_sum(v.x + v.y);
      float sq = wred_sum(v.x * v.x + v.y * v.y);
      float mu = s * 0.0078125f;
      float var = sq * 0.0078125f - mu * mu;
      float rstd = rsqrtf(var + 1e-5f);
      float2 o;
      o.x = (v.x - mu) * rstd * gg.x + cc.x;
      o.y = (v.y - mu) * rstd * gg.y + cc.y;
      *reinterpret_cast<float2*>(&outp[(size_t)tok * 128 + l2]) = o;
    }
  }
}

extern "C" void kernel_launch(void* const* d_in, const int* in_sizes, int n_in,
                              void* d_out, int out_size, void* d_ws, size_t ws_size,
                              hipStream_t stream) {
  const float* xq = (const float*)d_in[0];
  const float* kv = (const float*)d_in[1];
  const float* wkv = (const float*)d_in[2];
  const float* wq = (const float*)d_in[3];
  const float* wmh = (const float*)d_in[4];
  const float* bmh = (const float*)d_in[5];
  const float* w1 = (const float*)d_in[6];
  const float* b1 = (const float*)d_in[7];
  const float* w2 = (const float*)d_in[8];
  const float* b2 = (const float*)d_in[9];
  const float* g1 = (const float*)d_in[10];
  const float* bb1 = (const float*)d_in[11];
  const float* g2 = (const float*)d_in[12];
  const float* bb2 = (const float*)d_in[13];
  __half* ws = (__half*)d_ws;

  prep_weights<<<(WS_HALVES + 255) / 256, 256, 0, stream>>>(wq, wkv, wmh, w1, w2, ws);

  const int tokens = 32768;
  ca_mfma<<<tokens / TB, 256, 0, stream>>>(xq, kv, ws, bmh, b1, b2,
                                           g1, bb1, g2, bb2, (float*)d_out);
}

// Round 11
// 54.429 us; speedup vs baseline: 1.7168x; 1.7168x over previous
//
#include <hip/hip_runtime.h>
#include <hip/hip_fp16.h>

typedef _Float16 f16x8 __attribute__((ext_vector_type(8)));
typedef float f32x4 __attribute__((ext_vector_type(4)));
typedef unsigned int uint32;

#define LDW 136   // row stride in halves (272B: 16B-aligned)
#define TB  32    // tokens per block: two independent 16-token streams

// wait only lgkmcnt(0): vmcnt=63, expcnt=7, lgkmcnt=0 -> 0xC07F
#define WAITLGKM() do { __builtin_amdgcn_s_waitcnt(0xC07F); __builtin_amdgcn_sched_barrier(0); } while(0)

// lgkm-only barrier: leaves global (VGPR-destined) prefetches in flight.
#define BAR() do {                                          \
  asm volatile("s_waitcnt lgkmcnt(0)" ::: "memory");        \
  __builtin_amdgcn_sched_barrier(0);                        \
  __builtin_amdgcn_s_barrier();                             \
  __builtin_amdgcn_sched_barrier(0);                        \
} while (0)

union F16x8U { f16x8 v; __half2 h2[4]; uint2 u2[2]; uint4 u4; };

__device__ __forceinline__ uint32 pk2f(float a, float b) {
  __half2 h = __floats2half2_rn(a, b);
  return *reinterpret_cast<uint32*>(&h);
}
__device__ __forceinline__ float bcast(float v, int sl) {
  return __int_as_float(__builtin_amdgcn_readlane(__float_as_int(v), sl));
}
template <int CTRL, int RMASK = 0xF, int BMASK = 0xF>
__device__ __forceinline__ float dppmov(float v) {
  return __int_as_float(__builtin_amdgcn_update_dpp(
      0, __float_as_int(v), CTRL, RMASK, BMASK, true));
}
template <int PAT>
__device__ __forceinline__ float swzf(float v) {
  return __int_as_float(__builtin_amdgcn_ds_swizzle(__float_as_int(v), PAT));
}
// 64-lane sum via DPP (rocPRIM pattern) -> total broadcast via readlane(63)
__device__ __forceinline__ float wred_sum(float v) {
  v += dppmov<0x111>(v);                      // row_shr:1
  v += dppmov<0x112>(v);                      // row_shr:2
  v += dppmov<0x114>(v);                      // row_shr:4
  v += dppmov<0x118>(v);                      // row_shr:8
  v += dppmov<0x142, 0xA>(v);                 // row_bcast:15 (rows 1,3)
  v += dppmov<0x143, 0xC>(v);                 // row_bcast:31 (rows 2,3)
  return __int_as_float(__builtin_amdgcn_readlane(__float_as_int(v), 63));
}
__device__ __forceinline__ f16x8 ldsv8(const __half* p) {
  return *reinterpret_cast<const f16x8*>(p);   // ds_read_b128
}
__device__ __forceinline__ f32x4 mfma16(f16x8 a, f16x8 b, f32x4 c) {
  return __builtin_amdgcn_mfma_f32_16x16x32_f16(a, b, c, 0, 0, 0);
}
// packed C-frag store: C[m][n=fr] -> row-major act[tok=fr][c], 1x ds_write_b64
__device__ __forceinline__ void stp(__half* base, int fr, int fq, int nt, f32x4 a) {
  uint2 u; u.x = pk2f(a[0], a[1]); u.y = pk2f(a[2], a[3]);
  *reinterpret_cast<uint2*>(&base[fr * LDW + nt * 16 + fq * 4]) = u;
}

// ---- workspace layout (halves) ---- (same as R9)
#define OFF_WQ   0          // wqT  [c_out 128][c_in 128]
#define OFF_WK2  16384      // wk2  [h 4][i 128][d 40] : wkv[i][h*32+d] (d<32, pad 0)
#define OFF_WV   36864      // wvT  [c_out 128][i 128] : wkv[i][128+c]
#define OFF_WMH  53248      // wmhT
#define OFF_W1   69632      // w1T
#define OFF_W2   86016      // w2T
#define WS_HALVES 102400

__global__ void prep_weights(const float* __restrict__ wq, const float* __restrict__ wkv,
                             const float* __restrict__ wmh, const float* __restrict__ w1,
                             const float* __restrict__ w2, __half* __restrict__ ws) {
  int idx = blockIdx.x * 256 + threadIdx.x;
  if (idx >= WS_HALVES) return;
  float v;
  if (idx < OFF_WK2) {
    int t = idx, c = t >> 7, k = t & 127;
    v = wq[k * 128 + c];
  } else if (idx < OFF_WV) {
    int t = idx - OFF_WK2;
    int d = t % 40, row = t / 40;            // row = h*128 + i
    int h = row >> 7, i = row & 127;
    v = (d < 32) ? wkv[i * 256 + h * 32 + d] : 0.f;
  } else if (idx < OFF_WMH) {
    int t = idx - OFF_WV, c = t >> 7, k = t & 127;
    v = wkv[k * 256 + 128 + c];
  } else if (idx < OFF_W1) {
    int t = idx - OFF_WMH, c = t >> 7, k = t & 127;
    v = wmh[k * 128 + c];
  } else if (idx < OFF_W2) {
    int t = idx - OFF_W1, c = t >> 7, k = t & 127;
    v = w1[k * 128 + c];
  } else {
    int t = idx - OFF_W2, c = t >> 7, k = t & 127;
    v = w2[k * 128 + c];
  }
  ws[idx] = __float2half_rn(v);
}

// load W frags (2 c_out-tiles x 4 k-slices), used as MFMA *A* operand (shared by streams)
#define LOADB2(GOFF, NT0, NT1, BF) do {                                          \
  _Pragma("unroll")                                                              \
  for (int t_ = 0; t_ < 2; ++t_) {                                               \
    int nt_ = t_ ? (NT1) : (NT0);                                                \
    _Pragma("unroll")                                                            \
    for (int ks_ = 0; ks_ < 4; ++ks_)                                            \
      BF[t_][ks_] = *reinterpret_cast<const f16x8*>(                             \
          wsv + (GOFF) + (nt_*16 + fr)*128 + ks_*32 + fq*8);                     \
  } } while (0)

// two 16x16 tiles: A = weights (BF), B = activation tile (row-major [tok][c])
#define GEMM2(AT, BF, ACC0, ACC1) do {                                           \
  _Pragma("unroll")                                                              \
  for (int ks_ = 0; ks_ < 4; ++ks_) {                                            \
    f16x8 b_ = ldsv8(&(AT)[fr * LDW + ks_ * 32 + fq * 8]);                       \
    ACC0 = mfma16(BF[0][ks_], b_, ACC0);                                         \
    ACC1 = mfma16(BF[1][ks_], b_, ACC1);                                         \
  } } while (0)

__global__ void __launch_bounds__(256, 3) ca_mfma(
    const float* __restrict__ xq, const float* __restrict__ kvin,
    const __half* __restrict__ wsv,
    const float* __restrict__ bmh, const float* __restrict__ b1,
    const float* __restrict__ b2,
    const float* __restrict__ g1, const float* __restrict__ bb1,
    const float* __restrict__ g2, const float* __restrict__ bb2,
    float* __restrict__ outp)
{
  // LDS: 34816 + 17408 = 52224 B -> 3 blocks/CU
  __shared__ __half QWC[2 * 64 * LDW];   // per stream: qw/ctx rows; then Y/RES/H/V quadrants
  __shared__ __half UBUF[2 * 32 * LDW];  // per stream: Xh(0-15)->kvw->Ob ; Qb(16-31)->kvw

  const int tid = threadIdx.x;
  const int wv = tid >> 6, lane = tid & 63;
  const int fr = lane & 15, fq = lane >> 4;   // MFMA frag row / k-group
  const int tb = blockIdx.x * TB;
  const int ltb = wv * 4;

  __half* const QWs[2] = {QWC, QWC + 64 * LDW};
  __half* const Us[2]  = {UBUF, UBUF + 32 * LDW};
  // per stream: Xh = Us[st] rows 0-15; Qb = Us[st]+16*LDW; Ob = Us[st] rows 0-15 (after kvw)
  // Yb = QWs[st] rows 0-15; RESb +16; Hb +32; Vb +48

  const f32x4 ZZ = {0.f, 0.f, 0.f, 0.f};

  // ---- entry: prefetch token-0 kv for both streams + P1 W frags ----
  float4 pre[2][4];
#pragma unroll
  for (int st = 0; st < 2; ++st) {
    const float4* kv4 = reinterpret_cast<const float4*>(
        kvin + (size_t)(tb + st * 16 + ltb) * 1024);
    pre[st][0] = kv4[2 * lane];       pre[st][1] = kv4[2 * lane + 1];
    pre[st][2] = kv4[2 * lane + 128]; pre[st][3] = kv4[2 * lane + 129];
  }
  f16x8 bf[2][4];
  LOADB2(OFF_WQ, wv, 4 + wv, bf);

  // ---- Xh stage, both streams ----
  {
    int tok = tid >> 4, ko = (tid & 15) * 8;
#pragma unroll
    for (int st = 0; st < 2; ++st) {
      const float4* s0 = reinterpret_cast<const float4*>(
          xq + (size_t)(tb + st * 16 + tok) * 128 + ko);
      float4 a = s0[0], b = s0[1];
      uint4 u; u.x = pk2f(a.x, a.y); u.y = pk2f(a.z, a.w);
      u.z = pk2f(b.x, b.y); u.w = pk2f(b.z, b.w);
      *reinterpret_cast<uint4*>(&Us[st][tok * LDW + ko]) = u;
    }
  }
  BAR();  // 1: Xh ready; bf(wq)/kv pre stay in flight

  // ---- P1: Q = Wq(A) @ Xh(B) -> Qb[tok][c_out], both streams share bf ----
#pragma unroll
  for (int st = 0; st < 2; ++st) {
    f32x4 aA = ZZ, aB = ZZ;
    GEMM2(Us[st], bf, aA, aB);
    stp(Us[st] + 16 * LDW, fr, fq, wv, aA);
    stp(Us[st] + 16 * LDW, fr, fq, 4 + wv, aB);
  }
  // P2's A = wk2 rows (i), K=32 (shared)
  f16x8 bq[8];
#pragma unroll
  for (int nt = 0; nt < 8; ++nt)
    bq[nt] = *reinterpret_cast<const f16x8*>(
        wsv + OFF_WK2 + (wv * 128 + nt * 16 + fr) * 40 + fq * 8);
  BAR();  // 2: Qb ready; bq stays in flight; Xh reads done

  // ---- P2: qw[wv][tok][i] -> QWs[st][(wv*16+tok)][i] ----
#pragma unroll
  for (int st = 0; st < 2; ++st) {
    f16x8 aq = ldsv8(&Us[st][16 * LDW + fr * LDW + wv * 32 + fq * 8]);
#pragma unroll
    for (int nt = 0; nt < 8; ++nt) {
      f32x4 acc = mfma16(bq[nt], aq, ZZ);
      uint2 u; u.x = pk2f(acc[0], acc[1]); u.y = pk2f(acc[2], acc[3]);
      *reinterpret_cast<uint2*>(&QWs[st][(wv * 16 + fr) * LDW + nt * 16 + fq * 4]) = u;
    }
  }
  BAR();  // 3: qw ready; Xh/Qb reads done (kvw may overwrite)

  // ---- P3: wave-local attention, both streams interleaved (independent chains) ----
  {
    const int kr = lane >> 4, i8 = (lane & 15) * 8;
    const int l2 = 2 * lane;
    const float SCALE = 0.17677669529663687f;  // 1/sqrt(32)
#pragma unroll 1
    for (int lt = 0; lt < 4; ++lt) {
      const int ltok = ltb + lt;
      WAITLGKM();   // prior iter's ds_reads of kvw done (WAR), both streams
#pragma unroll
      for (int st = 0; st < 2; ++st) {
        __half* kvw = Us[st] + wv * 1088;
        uint4 u0, u1;
        u0.x = pk2f(pre[st][0].x, pre[st][0].y); u0.y = pk2f(pre[st][0].z, pre[st][0].w);
        u0.z = pk2f(pre[st][1].x, pre[st][1].y); u0.w = pk2f(pre[st][1].z, pre[st][1].w);
        u1.x = pk2f(pre[st][2].x, pre[st][2].y); u1.y = pk2f(pre[st][2].z, pre[st][2].w);
        u1.z = pk2f(pre[st][3].x, pre[st][3].y); u1.w = pk2f(pre[st][3].z, pre[st][3].w);
        *reinterpret_cast<uint4*>(&kvw[kr * LDW + i8]) = u0;        // rows 0..3
        *reinterpret_cast<uint4*>(&kvw[(4 + kr) * LDW + i8]) = u1;  // rows 4..7
      }
      if (lt < 3) {   // prefetch next token's kv, both streams
#pragma unroll
        for (int st = 0; st < 2; ++st) {
          const float4* kv4 = reinterpret_cast<const float4*>(
              kvin + (size_t)(tb + st * 16 + ltok + 1) * 1024);
          pre[st][0] = kv4[2 * lane];       pre[st][1] = kv4[2 * lane + 1];
          pre[st][2] = kv4[2 * lane + 128]; pre[st][3] = kv4[2 * lane + 129];
        }
      }
      WAITLGKM();   // kv writes visible within wave
      // sim via MFMA per stream (independent -> ILP)
      f32x4 acc[2];
#pragma unroll
      for (int st = 0; st < 2; ++st) {
        __half* kvw = Us[st] + wv * 1088;
        f32x4 a = ZZ;
#pragma unroll
        for (int ks = 0; ks < 4; ++ks) {
          f16x8 a_ = ldsv8(&QWs[st][((fr & 3) * 16 + ltok) * LDW + ks * 32 + fq * 8]);
          f16x8 b_ = ldsv8(&kvw[(fr & 7) * LDW + ks * 32 + fq * 8]);
          a = mfma16(a_, b_, a);
        }
        acc[st] = a;
      }
      // softmax over k (8 lanes), both streams' DPP chains interleave
      float at_[2][4];
#pragma unroll
      for (int st = 0; st < 2; ++st) {
#pragma unroll
        for (int r = 0; r < 4; ++r) {
          float s = acc[st][r] * SCALE;
          float mx = fmaxf(s, dppmov<0xB1>(s));
          mx = fmaxf(mx, dppmov<0x4E>(mx));
          mx = fmaxf(mx, swzf<0x101F>(mx));
          float e = __expf(s - mx);
          float dn = e + dppmov<0xB1>(e);
          dn += dppmov<0x4E>(dn);
          dn += swzf<0x101F>(dn);
          at_[st][r] = __fdividef(e, dn);
        }
      }
      // ctx[h][c] = sum_k at*kv ; lane owns cols 2*lane, 2*lane+1
#pragma unroll
      for (int st = 0; st < 2; ++st) {
        __half* kvw = Us[st] + wv * 1088;
        __half2 kvc[8];
#pragma unroll
        for (int k = 0; k < 8; ++k)
          kvc[k] = *reinterpret_cast<const __half2*>(&kvw[k * LDW + l2]);
#pragma unroll
        for (int h = 0; h < 4; ++h) {
          float c0 = 0.f, c1 = 0.f;
#pragma unroll
          for (int k = 0; k < 8; ++k) {
            float a = bcast(at_[st][h], k);
            float2 kf = __half22float2(kvc[k]);
            c0 = fmaf(a, kf.x, c0);
            c1 = fmaf(a, kf.y, c1);
          }
          *reinterpret_cast<__half2*>(&QWs[st][(h * 16 + ltok) * LDW + l2]) =
              __floats2half2_rn(c0, c1);
        }
      }
    }
  }
  LOADB2(OFF_WV, wv, 4 + wv, bf);
  BAR();  // 4: ctx ready; kvw reads done; bf(wv) stays in flight

  // ---- P4: out = WvT(A) @ ctx(B) -> Ob[tok][c], both streams ----
  float2 xr[2][4];
#pragma unroll
  for (int st = 0; st < 2; ++st)
#pragma unroll
    for (int lt = 0; lt < 4; ++lt) {
      int tok = tb + st * 16 + ltb + lt;
      xr[st][lt] = *reinterpret_cast<const float2*>(&xq[(size_t)tok * 128 + 2 * lane]);
    }
  {
    const int h1 = wv >> 1, h2 = 2 + (wv >> 1);
#pragma unroll
    for (int st = 0; st < 2; ++st) {
      f32x4 a1c = ZZ, a2c = ZZ;
#pragma unroll
      for (int ks = 0; ks < 4; ++ks) {
        f16x8 b1f = ldsv8(&QWs[st][(h1 * 16 + fr) * LDW + ks * 32 + fq * 8]);
        a1c = mfma16(bf[0][ks], b1f, a1c);
        f16x8 b2f = ldsv8(&QWs[st][(h2 * 16 + fr) * LDW + ks * 32 + fq * 8]);
        a2c = mfma16(bf[1][ks], b2f, a2c);
      }
      stp(Us[st], fr, fq, wv, a1c);        // Ob aliases stream slot 0
      stp(Us[st], fr, fq, 4 + wv, a2c);
    }
  }
  LOADB2(OFF_WMH, wv, 4 + wv, bf);
  BAR();  // 5: Ob ready; ctx reads done; bf(wmh) stays in flight

  // ---- P5: y = Wmh(A) @ out(B) -> Yb[tok][c] ----
#pragma unroll
  for (int st = 0; st < 2; ++st) {
    f32x4 aA = ZZ, aB = ZZ;
    GEMM2(Us[st], bf, aA, aB);
    stp(QWs[st], fr, fq, wv, aA);
    stp(QWs[st], fr, fq, 4 + wv, aB);
  }
  LOADB2(OFF_W1, wv, 4 + wv, bf);
  BAR();  // 6: Yb ready; bf(w1) stays in flight

  // ---- LN1 + residual -> RESb (DPP reductions), both streams ----
  {
    const int l2 = 2 * lane;
    float2 bm = *reinterpret_cast<const float2*>(&bmh[l2]);
    float2 gg = *reinterpret_cast<const float2*>(&g1[l2]);
    float2 cc = *reinterpret_cast<const float2*>(&bb1[l2]);
#pragma unroll
    for (int st = 0; st < 2; ++st)
#pragma unroll
      for (int lt = 0; lt < 4; ++lt) {
        int row = ltb + lt;
        float2 y = __half22float2(
            *reinterpret_cast<const __half2*>(&QWs[st][row * LDW + l2]));
        float v0 = y.x + bm.x, v1 = y.y + bm.y;
        float s = wred_sum(v0 + v1);
        float sq = wred_sum(v0 * v0 + v1 * v1);
        float mu = s * 0.0078125f;
        float var = sq * 0.0078125f - mu * mu;
        float rstd = rsqrtf(var + 1e-5f);
        float r0 = (v0 - mu) * rstd * gg.x + cc.x + xr[st][lt].x;
        float r1 = (v1 - mu) * rstd * gg.y + cc.y + xr[st][lt].y;
        *reinterpret_cast<__half2*>(&QWs[st][(16 + row) * LDW + l2]) =
            __floats2half2_rn(r0, r1);
      }
  }
  BAR();  // 7: RESb ready

  // ---- P6: h = gelu(W1(A) @ res(B) + b1) -> Hb ----
  {
    int c0 = wv * 16 + fq * 4, c1 = 64 + wv * 16 + fq * 4;
    float4 b1a = *reinterpret_cast<const float4*>(&b1[c0]);
    float4 b1b = *reinterpret_cast<const float4*>(&b1[c1]);
#pragma unroll
    for (int st = 0; st < 2; ++st) {
      f32x4 aA = ZZ, aB = ZZ;
      GEMM2(QWs[st] + 16 * LDW, bf, aA, aB);
      uint2 ua, ub;
      float t0, t1;
      t0 = aA[0] + b1a.x; t0 = 0.5f * t0 * (1.f + erff(t0 * 0.70710678118654752f));
      t1 = aA[1] + b1a.y; t1 = 0.5f * t1 * (1.f + erff(t1 * 0.70710678118654752f));
      ua.x = pk2f(t0, t1);
      t0 = aA[2] + b1a.z; t0 = 0.5f * t0 * (1.f + erff(t0 * 0.70710678118654752f));
      t1 = aA[3] + b1a.w; t1 = 0.5f * t1 * (1.f + erff(t1 * 0.70710678118654752f));
      ua.y = pk2f(t0, t1);
      t0 = aB[0] + b1b.x; t0 = 0.5f * t0 * (1.f + erff(t0 * 0.70710678118654752f));
      t1 = aB[1] + b1b.y; t1 = 0.5f * t1 * (1.f + erff(t1 * 0.70710678118654752f));
      ub.x = pk2f(t0, t1);
      t0 = aB[2] + b1b.z; t0 = 0.5f * t0 * (1.f + erff(t0 * 0.70710678118654752f));
      t1 = aB[3] + b1b.w; t1 = 0.5f * t1 * (1.f + erff(t1 * 0.70710678118654752f));
      ub.y = pk2f(t0, t1);
      *reinterpret_cast<uint2*>(&QWs[st][(32 + fr) * LDW + c0]) = ua;
      *reinterpret_cast<uint2*>(&QWs[st][(32 + fr) * LDW + c1]) = ub;
    }
  }
  LOADB2(OFF_W2, wv, 4 + wv, bf);
  BAR();  // 8: Hb ready; bf(w2) stays in flight

  // ---- P7: v = W2(A) @ h(B) + b2 + res -> Vb ----
  {
    int c0 = wv * 16 + fq * 4, c1 = 64 + wv * 16 + fq * 4;
    float4 b2a = *reinterpret_cast<const float4*>(&b2[c0]);
    float4 b2b = *reinterpret_cast<const float4*>(&b2[c1]);
#pragma unroll
    for (int st = 0; st < 2; ++st) {
      f32x4 aA = ZZ, aB = ZZ;
      GEMM2(QWs[st] + 32 * LDW, bf, aA, aB);
      F16x8U ra, rb;
      ra.u2[0] = *reinterpret_cast<const uint2*>(&QWs[st][(16 + fr) * LDW + c0]);
      rb.u2[0] = *reinterpret_cast<const uint2*>(&QWs[st][(16 + fr) * LDW + c1]);
      uint2 ua, ub;
      float2 p0 = __half22float2(ra.h2[0]), p1 = __half22float2(ra.h2[1]);
      ua.x = pk2f(aA[0] + b2a.x + p0.x, aA[1] + b2a.y + p0.y);
      ua.y = pk2f(aA[2] + b2a.z + p1.x, aA[3] + b2a.w + p1.y);
      float2 p2 = __half22float2(rb.h2[0]), p3 = __half22float2(rb.h2[1]);
      ub.x = pk2f(aB[0] + b2b.x + p2.x, aB[1] + b2b.y + p2.y);
      ub.y = pk2f(aB[2] + b2b.z + p3.x, aB[3] + b2b.w + p3.y);
      *reinterpret_cast<uint2*>(&QWs[st][(48 + fr) * LDW + c0]) = ua;
      *reinterpret_cast<uint2*>(&QWs[st][(48 + fr) * LDW + c1]) = ub;
    }
  }
  BAR();  // 9: Vb ready

  // ---- LN2 + store (DPP reductions), both streams ----
  {
    const int l2 = 2 * lane;
    float2 gg = *reinterpret_cast<const float2*>(&g2[l2]);
    float2 cc = *reinterpret_cast<const float2*>(&bb2[l2]);
#pragma unroll
    for (int st = 0; st < 2; ++st)
#pragma unroll
      for (int lt = 0; lt < 4; ++lt) {
        int row = ltb + lt, tok = tb + st * 16 + row;
        float2 v = __half22float2(
            *reinterpret_cast<const __half2*>(&QWs[st][(48 + row) * LDW + l2]));
        float s = wred_sum(v.x + v.y);
        float sq = wred_sum(v.x * v.x + v.y * v.y);
        float mu = s * 0.0078125f;
        float var = sq * 0.0078125f - mu * mu;
        float rstd = rsqrtf(var + 1e-5f);
        float2 o;
        o.x = (v.x - mu) * rstd * gg.x + cc.x;
        o.y = (v.y - mu) * rstd * gg.y + cc.y;
        *reinterpret_cast<float2*>(&outp[(size_t)tok * 128 + l2]) = o;
      }
  }
}

extern "C" void kernel_launch(void* const* d_in, const int* in_sizes, int n_in,
                              void* d_out, int out_size, void* d_ws, size_t ws_size,
                              hipStream_t stream) {
  const float* xq = (const float*)d_in[0];
  const float* kv = (const float*)d_in[1];
  const float* wkv = (const float*)d_in[2];
  const float* wq = (const float*)d_in[3];
  const float* wmh = (const float*)d_in[4];
  const float* bmh = (const float*)d_in[5];
  const float* w1 = (const float*)d_in[6];
  const float* b1 = (const float*)d_in[7];
  const float* w2 = (const float*)d_in[8];
  const float* b2 = (const float*)d_in[9];
  const float* g1 = (const float*)d_in[10];
  const float* bb1 = (const float*)d_in[11];
  const float* g2 = (const float*)d_in[12];
  const float* bb2 = (const float*)d_in[13];
  __half* ws = (__half*)d_ws;

  prep_weights<<<(WS_HALVES + 255) / 256, 256, 0, stream>>>(wq, wkv, wmh, w1, w2, ws);

  const int tokens = 32768;
  ca_mfma<<<tokens / TB, 256, 0, stream>>>(xq, kv, ws, bmh, b1, b2,
                                           g1, bb1, g2, bb2, (float*)d_out);
}

// Round 12
// 53.767 us; speedup vs baseline: 1.7379x; 1.0123x over previous
//
#include <hip/hip_runtime.h>
#include <hip/hip_fp16.h>

typedef _Float16 f16x8 __attribute__((ext_vector_type(8)));
typedef float f32x4 __attribute__((ext_vector_type(4)));
typedef unsigned int uint32;

#define LDW 136   // row stride in halves (272B: 16B-aligned)
#define TB  32    // tokens per block: two independent 16-token streams

// wait only lgkmcnt(0): vmcnt=63, expcnt=7, lgkmcnt=0 -> 0xC07F
#define WAITLGKM() do { __builtin_amdgcn_s_waitcnt(0xC07F); __builtin_amdgcn_sched_barrier(0); } while(0)

// lgkm-only barrier: leaves global (VGPR-destined) prefetches in flight.
#define BAR() do {                                          \
  asm volatile("s_waitcnt lgkmcnt(0)" ::: "memory");        \
  __builtin_amdgcn_sched_barrier(0);                        \
  __builtin_amdgcn_s_barrier();                             \
  __builtin_amdgcn_sched_barrier(0);                        \
} while (0)

union F16x8U { f16x8 v; __half2 h2[4]; uint2 u2[2]; uint4 u4; };

__device__ __forceinline__ uint32 pk2f(float a, float b) {
  __half2 h = __floats2half2_rn(a, b);
  return *reinterpret_cast<uint32*>(&h);
}
__device__ __forceinline__ float bcast(float v, int sl) {
  return __int_as_float(__builtin_amdgcn_readlane(__float_as_int(v), sl));
}
template <int CTRL, int RMASK = 0xF, int BMASK = 0xF>
__device__ __forceinline__ float dppmov(float v) {
  return __int_as_float(__builtin_amdgcn_update_dpp(
      0, __float_as_int(v), CTRL, RMASK, BMASK, true));
}
template <int PAT>
__device__ __forceinline__ float swzf(float v) {
  return __int_as_float(__builtin_amdgcn_ds_swizzle(__float_as_int(v), PAT));
}
__device__ __forceinline__ f16x8 ldsv8(const __half* p) {
  return *reinterpret_cast<const f16x8*>(p);   // ds_read_b128
}
__device__ __forceinline__ f32x4 mfma16(f16x8 a, f16x8 b, f32x4 c) {
  return __builtin_amdgcn_mfma_f32_16x16x32_f16(a, b, c, 0, 0, 0);
}
// packed C-frag store: C[m][n=fr] -> row-major act[tok=fr][c], 1x ds_write_b64
__device__ __forceinline__ void stp(__half* base, int fr, int fq, int nt, f32x4 a) {
  uint2 u; u.x = pk2f(a[0], a[1]); u.y = pk2f(a[2], a[3]);
  *reinterpret_cast<uint2*>(&base[fr * LDW + nt * 16 + fq * 4]) = u;
}

// ---- workspace layout (halves) ----
#define OFF_WQ   0          // wqT  [c_out 128][c_in 128]
#define OFF_WK2  16384      // wk2  [h 4][i 128][d 40] : wkv[i][h*32+d] (d<32, pad 0)
#define OFF_WV   36864      // wvT  [c_out 128][i 128] : wkv[i][128+c]
#define OFF_WMH  53248      // wmhT
#define OFF_W1   69632      // w1T
#define OFF_W2   86016      // w2T
#define WS_HALVES 102400

__global__ void prep_weights(const float* __restrict__ wq, const float* __restrict__ wkv,
                             const float* __restrict__ wmh, const float* __restrict__ w1,
                             const float* __restrict__ w2, __half* __restrict__ ws) {
  int idx = blockIdx.x * 256 + threadIdx.x;
  if (idx >= WS_HALVES) return;
  float v;
  if (idx < OFF_WK2) {
    int t = idx, c = t >> 7, k = t & 127;
    v = wq[k * 128 + c];
  } else if (idx < OFF_WV) {
    int t = idx - OFF_WK2;
    int d = t % 40, row = t / 40;            // row = h*128 + i
    int h = row >> 7, i = row & 127;
    v = (d < 32) ? wkv[i * 256 + h * 32 + d] : 0.f;
  } else if (idx < OFF_WMH) {
    int t = idx - OFF_WV, c = t >> 7, k = t & 127;
    v = wkv[k * 256 + 128 + c];
  } else if (idx < OFF_W1) {
    int t = idx - OFF_WMH, c = t >> 7, k = t & 127;
    v = wmh[k * 128 + c];
  } else if (idx < OFF_W2) {
    int t = idx - OFF_W1, c = t >> 7, k = t & 127;
    v = w1[k * 128 + c];
  } else {
    int t = idx - OFF_W2, c = t >> 7, k = t & 127;
    v = w2[k * 128 + c];
  }
  ws[idx] = __float2half_rn(v);
}

// load W frags (2 c_out-tiles x 4 k-slices), used as MFMA *A* operand (shared by streams)
#define LOADB2(GOFF, NT0, NT1, BF) do {                                          \
  _Pragma("unroll")                                                              \
  for (int t_ = 0; t_ < 2; ++t_) {                                               \
    int nt_ = t_ ? (NT1) : (NT0);                                                \
    _Pragma("unroll")                                                            \
    for (int ks_ = 0; ks_ < 4; ++ks_)                                            \
      BF[t_][ks_] = *reinterpret_cast<const f16x8*>(                             \
          wsv + (GOFF) + (nt_*16 + fr)*128 + ks_*32 + fq*8);                     \
  } } while (0)

// two 16x16 tiles: A = weights (BF), B = activation tile (row-major [tok][c])
#define GEMM2(AT, BF, ACC0, ACC1) do {                                           \
  _Pragma("unroll")                                                              \
  for (int ks_ = 0; ks_ < 4; ++ks_) {                                            \
    f16x8 b_ = ldsv8(&(AT)[fr * LDW + ks_ * 32 + fq * 8]);                       \
    ACC0 = mfma16(BF[0][ks_], b_, ACC0);                                         \
    ACC1 = mfma16(BF[1][ks_], b_, ACC1);                                         \
  } } while (0)

__global__ void __launch_bounds__(256, 3) ca_mfma(
    const float* __restrict__ xq, const float* __restrict__ kvin,
    const __half* __restrict__ wsv,
    const float* __restrict__ bmh, const float* __restrict__ b1,
    const float* __restrict__ b2,
    const float* __restrict__ g1, const float* __restrict__ bb1,
    const float* __restrict__ g2, const float* __restrict__ bb2,
    float* __restrict__ outp)
{
  // LDS: 34816 + 17408 + 1024 = 53248 B -> 3 blocks/CU
  __shared__ __half QWC[2 * 64 * LDW];   // per stream: qw/ctx rows 0-63; RESb 16-31, Hb 32-47 reuse
  __shared__ __half UBUF[2 * 32 * LDW];  // per stream: Xh(0-15)/Qb(16-31) -> kvw -> Ob(0-15)
  __shared__ float  PART[2][2][16][4];   // [stream][s|sq][tok][wave] LN partials

  const int tid = threadIdx.x;
  const int wv = tid >> 6, lane = tid & 63;
  const int fr = lane & 15, fq = lane >> 4;   // MFMA frag row / k-group
  const int tb = blockIdx.x * TB;
  const int ltb = wv * 4;
  const int cA = wv * 16 + fq * 4, cB = 64 + cA;   // this lane's C-frag columns

  __half* const QWs[2] = {QWC, QWC + 64 * LDW};
  __half* const Us[2]  = {UBUF, UBUF + 32 * LDW};

  const f32x4 ZZ = {0.f, 0.f, 0.f, 0.f};

  // ---- entry: prefetch token-0 kv for both streams + P1 W frags (wave-local tiles) ----
  float4 pre[2][4];
#pragma unroll
  for (int st = 0; st < 2; ++st) {
    const float4* kv4 = reinterpret_cast<const float4*>(
        kvin + (size_t)(tb + st * 16 + ltb) * 1024);
    pre[st][0] = kv4[2 * lane];       pre[st][1] = kv4[2 * lane + 1];
    pre[st][2] = kv4[2 * lane + 128]; pre[st][3] = kv4[2 * lane + 129];
  }
  f16x8 bf[2][4];
  LOADB2(OFF_WQ, 2 * wv, 2 * wv + 1, bf);   // wave computes the Q-cols its own P2 needs

  // ---- Xh stage, both streams ----
  {
    int tok = tid >> 4, ko = (tid & 15) * 8;
#pragma unroll
    for (int st = 0; st < 2; ++st) {
      const float4* s0 = reinterpret_cast<const float4*>(
          xq + (size_t)(tb + st * 16 + tok) * 128 + ko);
      float4 a = s0[0], b = s0[1];
      uint4 u; u.x = pk2f(a.x, a.y); u.y = pk2f(a.z, a.w);
      u.z = pk2f(b.x, b.y); u.w = pk2f(b.z, b.w);
      *reinterpret_cast<uint4*>(&Us[st][tok * LDW + ko]) = u;
    }
  }
  BAR();  // A: Xh ready; bf(wq)/kv pre stay in flight

  // ---- P1: Q cols [32wv,32wv+32) for all 16 tokens, both streams ----
#pragma unroll
  for (int st = 0; st < 2; ++st) {
    f32x4 aA = ZZ, aB = ZZ;
    GEMM2(Us[st], bf, aA, aB);
    stp(Us[st] + 16 * LDW, fr, fq, 2 * wv, aA);
    stp(Us[st] + 16 * LDW, fr, fq, 2 * wv + 1, aB);
  }
  // P2's A = wk2 rows (i), K=32 (shared)
  f16x8 bq[8];
#pragma unroll
  for (int nt = 0; nt < 8; ++nt)
    bq[nt] = *reinterpret_cast<const f16x8*>(
        wsv + OFF_WK2 + (wv * 128 + nt * 16 + fr) * 40 + fq * 8);
  WAITLGKM();  // P1->P2 is wave-local (cols match): no block barrier needed

  // ---- P2: qw[wv][tok][i] -> QWs[st][(wv*16+tok)][i] ----
#pragma unroll
  for (int st = 0; st < 2; ++st) {
    f16x8 aq = ldsv8(&Us[st][16 * LDW + fr * LDW + wv * 32 + fq * 8]);
#pragma unroll
    for (int nt = 0; nt < 8; ++nt) {
      f32x4 acc = mfma16(bq[nt], aq, ZZ);
      uint2 u; u.x = pk2f(acc[0], acc[1]); u.y = pk2f(acc[2], acc[3]);
      *reinterpret_cast<uint2*>(&QWs[st][(wv * 16 + fr) * LDW + nt * 16 + fq * 4]) = u;
    }
  }
  BAR();  // B: qw ready; Xh/Qb reads done (kvw may overwrite)

  // ---- P3: wave-local attention, both streams interleaved ----
  {
    const int kr = lane >> 4, i8 = (lane & 15) * 8;
    const int l2 = 2 * lane;
    const float SCALE = 0.17677669529663687f;  // 1/sqrt(32)
#pragma unroll 1
    for (int lt = 0; lt < 4; ++lt) {
      const int ltok = ltb + lt;
      WAITLGKM();   // prior iter's ds_reads of kvw done (WAR)
#pragma unroll
      for (int st = 0; st < 2; ++st) {
        __half* kvw = Us[st] + wv * 1088;
        uint4 u0, u1;
        u0.x = pk2f(pre[st][0].x, pre[st][0].y); u0.y = pk2f(pre[st][0].z, pre[st][0].w);
        u0.z = pk2f(pre[st][1].x, pre[st][1].y); u0.w = pk2f(pre[st][1].z, pre[st][1].w);
        u1.x = pk2f(pre[st][2].x, pre[st][2].y); u1.y = pk2f(pre[st][2].z, pre[st][2].w);
        u1.z = pk2f(pre[st][3].x, pre[st][3].y); u1.w = pk2f(pre[st][3].z, pre[st][3].w);
        *reinterpret_cast<uint4*>(&kvw[kr * LDW + i8]) = u0;        // rows 0..3
        *reinterpret_cast<uint4*>(&kvw[(4 + kr) * LDW + i8]) = u1;  // rows 4..7
      }
      if (lt < 3) {
#pragma unroll
        for (int st = 0; st < 2; ++st) {
          const float4* kv4 = reinterpret_cast<const float4*>(
              kvin + (size_t)(tb + st * 16 + ltok + 1) * 1024);
          pre[st][0] = kv4[2 * lane];       pre[st][1] = kv4[2 * lane + 1];
          pre[st][2] = kv4[2 * lane + 128]; pre[st][3] = kv4[2 * lane + 129];
        }
      }
      WAITLGKM();   // kv writes visible within wave
      f32x4 acc[2];
#pragma unroll
      for (int st = 0; st < 2; ++st) {
        __half* kvw = Us[st] + wv * 1088;
        f32x4 a = ZZ;
#pragma unroll
        for (int ks = 0; ks < 4; ++ks) {
          f16x8 a_ = ldsv8(&QWs[st][((fr & 3) * 16 + ltok) * LDW + ks * 32 + fq * 8]);
          f16x8 b_ = ldsv8(&kvw[(fr & 7) * LDW + ks * 32 + fq * 8]);
          a = mfma16(a_, b_, a);
        }
        acc[st] = a;
      }
      float at_[2][4];
#pragma unroll
      for (int st = 0; st < 2; ++st) {
#pragma unroll
        for (int r = 0; r < 4; ++r) {
          float s = acc[st][r] * SCALE;
          float mx = fmaxf(s, dppmov<0xB1>(s));
          mx = fmaxf(mx, dppmov<0x4E>(mx));
          mx = fmaxf(mx, swzf<0x101F>(mx));
          float e = __expf(s - mx);
          float dn = e + dppmov<0xB1>(e);
          dn += dppmov<0x4E>(dn);
          dn += swzf<0x101F>(dn);
          at_[st][r] = __fdividef(e, dn);
        }
      }
#pragma unroll
      for (int st = 0; st < 2; ++st) {
        __half* kvw = Us[st] + wv * 1088;
        __half2 kvc[8];
#pragma unroll
        for (int k = 0; k < 8; ++k)
          kvc[k] = *reinterpret_cast<const __half2*>(&kvw[k * LDW + l2]);
#pragma unroll
        for (int h = 0; h < 4; ++h) {
          float c0 = 0.f, c1 = 0.f;
#pragma unroll
          for (int k = 0; k < 8; ++k) {
            float a = bcast(at_[st][h], k);
            float2 kf = __half22float2(kvc[k]);
            c0 = fmaf(a, kf.x, c0);
            c1 = fmaf(a, kf.y, c1);
          }
          *reinterpret_cast<__half2*>(&QWs[st][(h * 16 + ltok) * LDW + l2]) =
              __floats2half2_rn(c0, c1);
        }
      }
    }
  }
  LOADB2(OFF_WV, wv, 4 + wv, bf);
  BAR();  // C: ctx ready; kvw reads done; bf(wv) in flight

  // ---- P4: out = WvT(A) @ ctx(B) -> Ob[tok][c] ----
  {
    const int h1 = wv >> 1, h2 = 2 + (wv >> 1);
#pragma unroll
    for (int st = 0; st < 2; ++st) {
      f32x4 a1c = ZZ, a2c = ZZ;
#pragma unroll
      for (int ks = 0; ks < 4; ++ks) {
        f16x8 b1f = ldsv8(&QWs[st][(h1 * 16 + fr) * LDW + ks * 32 + fq * 8]);
        a1c = mfma16(bf[0][ks], b1f, a1c);
        f16x8 b2f = ldsv8(&QWs[st][(h2 * 16 + fr) * LDW + ks * 32 + fq * 8]);
        a2c = mfma16(bf[1][ks], b2f, a2c);
      }
      stp(Us[st], fr, fq, wv, a1c);
      stp(Us[st], fr, fq, 4 + wv, a2c);
    }
  }
  LOADB2(OFF_WMH, wv, 4 + wv, bf);
  // prefetch this lane's residual x in C-frag layout (token fr, cols cA/cB)
  float4 xqA[2], xqB[2];
#pragma unroll
  for (int st = 0; st < 2; ++st) {
    const float* xrow = xq + (size_t)(tb + st * 16 + fr) * 128;
    xqA[st] = *reinterpret_cast<const float4*>(xrow + cA);
    xqB[st] = *reinterpret_cast<const float4*>(xrow + cB);
  }
  BAR();  // D: Ob ready; bf(wmh)/xq in flight

  // ---- P5 + LN1 stats in C-frag layout (token = fr, all tokens in parallel) ----
  float vv[2][8];
  {
    float4 bmA = *reinterpret_cast<const float4*>(&bmh[cA]);
    float4 bmB = *reinterpret_cast<const float4*>(&bmh[cB]);
#pragma unroll
    for (int st = 0; st < 2; ++st) {
      f32x4 aA = ZZ, aB = ZZ;
      GEMM2(Us[st], bf, aA, aB);
      vv[st][0] = aA[0] + bmA.x; vv[st][1] = aA[1] + bmA.y;
      vv[st][2] = aA[2] + bmA.z; vv[st][3] = aA[3] + bmA.w;
      vv[st][4] = aB[0] + bmB.x; vv[st][5] = aB[1] + bmB.y;
      vv[st][6] = aB[2] + bmB.z; vv[st][7] = aB[3] + bmB.w;
      float s = 0.f, sq = 0.f;
#pragma unroll
      for (int r = 0; r < 8; ++r) { s += vv[st][r]; sq = fmaf(vv[st][r], vv[st][r], sq); }
      s += swzf<0x401F>(s);  s += __shfl_xor(s, 32);    // combine 4 fq-lanes
      sq += swzf<0x401F>(sq); sq += __shfl_xor(sq, 32);
      if (fq == 0) { PART[st][0][fr][wv] = s; PART[st][1][fr][wv] = sq; }
    }
  }
  LOADB2(OFF_W1, wv, 4 + wv, bf);
  BAR();  // E': LN1 partials ready; bf(w1) in flight

  // ---- LN1 finish: combine 4 wave-partials, normalize own cols, + residual -> RESb ----
  {
    float4 gA = *reinterpret_cast<const float4*>(&g1[cA]);
    float4 gB = *reinterpret_cast<const float4*>(&g1[cB]);
    float4 cAv = *reinterpret_cast<const float4*>(&bb1[cA]);
    float4 cBv = *reinterpret_cast<const float4*>(&bb1[cB]);
#pragma unroll
    for (int st = 0; st < 2; ++st) {
      float4 ps = *reinterpret_cast<const float4*>(&PART[st][0][fr][0]);
      float4 pq = *reinterpret_cast<const float4*>(&PART[st][1][fr][0]);
      float su = (ps.x + ps.y) + (ps.z + ps.w);
      float squ = (pq.x + pq.y) + (pq.z + pq.w);
      float mu = su * 0.0078125f;
      float var = squ * 0.0078125f - mu * mu;
      float rstd = rsqrtf(var + 1e-5f);
      float rA0 = (vv[st][0] - mu) * rstd * gA.x + cAv.x + xqA[st].x;
      float rA1 = (vv[st][1] - mu) * rstd * gA.y + cAv.y + xqA[st].y;
      float rA2 = (vv[st][2] - mu) * rstd * gA.z + cAv.z + xqA[st].z;
      float rA3 = (vv[st][3] - mu) * rstd * gA.w + cAv.w + xqA[st].w;
      float rB0 = (vv[st][4] - mu) * rstd * gB.x + cBv.x + xqB[st].x;
      float rB1 = (vv[st][5] - mu) * rstd * gB.y + cBv.y + xqB[st].y;
      float rB2 = (vv[st][6] - mu) * rstd * gB.z + cBv.z + xqB[st].z;
      float rB3 = (vv[st][7] - mu) * rstd * gB.w + cBv.w + xqB[st].w;
      uint2 ua, ub;
      ua.x = pk2f(rA0, rA1); ua.y = pk2f(rA2, rA3);
      ub.x = pk2f(rB0, rB1); ub.y = pk2f(rB2, rB3);
      *reinterpret_cast<uint2*>(&QWs[st][(16 + fr) * LDW + cA]) = ua;  // RESb
      *reinterpret_cast<uint2*>(&QWs[st][(16 + fr) * LDW + cB]) = ub;
    }
  }
  BAR();  // E: RESb ready

  // ---- P6: h = gelu(W1(A) @ res(B) + b1) -> Hb (QWs rows 32-47) ----
  {
    float4 b1a = *reinterpret_cast<const float4*>(&b1[cA]);
    float4 b1b = *reinterpret_cast<const float4*>(&b1[cB]);
#pragma unroll
    for (int st = 0; st < 2; ++st) {
      f32x4 aA = ZZ, aB = ZZ;
      GEMM2(QWs[st] + 16 * LDW, bf, aA, aB);
      uint2 ua, ub;
      float t0, t1;
      t0 = aA[0] + b1a.x; t0 = 0.5f * t0 * (1.f + erff(t0 * 0.70710678118654752f));
      t1 = aA[1] + b1a.y; t1 = 0.5f * t1 * (1.f + erff(t1 * 0.70710678118654752f));
      ua.x = pk2f(t0, t1);
      t0 = aA[2] + b1a.z; t0 = 0.5f * t0 * (1.f + erff(t0 * 0.70710678118654752f));
      t1 = aA[3] + b1a.w; t1 = 0.5f * t1 * (1.f + erff(t1 * 0.70710678118654752f));
      ua.y = pk2f(t0, t1);
      t0 = aB[0] + b1b.x; t0 = 0.5f * t0 * (1.f + erff(t0 * 0.70710678118654752f));
      t1 = aB[1] + b1b.y; t1 = 0.5f * t1 * (1.f + erff(t1 * 0.70710678118654752f));
      ub.x = pk2f(t0, t1);
      t0 = aB[2] + b1b.z; t0 = 0.5f * t0 * (1.f + erff(t0 * 0.70710678118654752f));
      t1 = aB[3] + b1b.w; t1 = 0.5f * t1 * (1.f + erff(t1 * 0.70710678118654752f));
      ub.y = pk2f(t0, t1);
      *reinterpret_cast<uint2*>(&QWs[st][(32 + fr) * LDW + cA]) = ua;
      *reinterpret_cast<uint2*>(&QWs[st][(32 + fr) * LDW + cB]) = ub;
    }
  }
  LOADB2(OFF_W2, wv, 4 + wv, bf);
  BAR();  // F: Hb ready; bf(w2) in flight

  // ---- P7 + LN2 stats in C-frag layout ----
  float ww[2][8];
  {
    float4 b2a = *reinterpret_cast<const float4*>(&b2[cA]);
    float4 b2b = *reinterpret_cast<const float4*>(&b2[cB]);
#pragma unroll
    for (int st = 0; st < 2; ++st) {
      f32x4 aA = ZZ, aB = ZZ;
      GEMM2(QWs[st] + 32 * LDW, bf, aA, aB);
      F16x8U ra, rb;
      ra.u2[0] = *reinterpret_cast<const uint2*>(&QWs[st][(16 + fr) * LDW + cA]);
      rb.u2[0] = *reinterpret_cast<const uint2*>(&QWs[st][(16 + fr) * LDW + cB]);
      float2 p0 = __half22float2(ra.h2[0]), p1 = __half22float2(ra.h2[1]);
      float2 p2 = __half22float2(rb.h2[0]), p3 = __half22float2(rb.h2[1]);
      ww[st][0] = aA[0] + b2a.x + p0.x; ww[st][1] = aA[1] + b2a.y + p0.y;
      ww[st][2] = aA[2] + b2a.z + p1.x; ww[st][3] = aA[3] + b2a.w + p1.y;
      ww[st][4] = aB[0] + b2b.x + p2.x; ww[st][5] = aB[1] + b2b.y + p2.y;
      ww[st][6] = aB[2] + b2b.z + p3.x; ww[st][7] = aB[3] + b2b.w + p3.y;
      float s = 0.f, sq = 0.f;
#pragma unroll
      for (int r = 0; r < 8; ++r) { s += ww[st][r]; sq = fmaf(ww[st][r], ww[st][r], sq); }
      s += swzf<0x401F>(s);  s += __shfl_xor(s, 32);
      sq += swzf<0x401F>(sq); sq += __shfl_xor(sq, 32);
      if (fq == 0) { PART[st][0][fr][wv] = s; PART[st][1][fr][wv] = sq; }
    }
  }
  BAR();  // G: LN2 partials ready

  // ---- LN2 finish + coalesced float4 store straight from C-frag ----
  {
    float4 gA = *reinterpret_cast<const float4*>(&g2[cA]);
    float4 gB = *reinterpret_cast<const float4*>(&g2[cB]);
    float4 cAv = *reinterpret_cast<const float4*>(&bb2[cA]);
    float4 cBv = *reinterpret_cast<const float4*>(&bb2[cB]);
#pragma unroll
    for (int st = 0; st < 2; ++st) {
      float4 ps = *reinterpret_cast<const float4*>(&PART[st][0][fr][0]);
      float4 pq = *reinterpret_cast<const float4*>(&PART[st][1][fr][0]);
      float su = (ps.x + ps.y) + (ps.z + ps.w);
      float squ = (pq.x + pq.y) + (pq.z + pq.w);
      float mu = su * 0.0078125f;
      float var = squ * 0.0078125f - mu * mu;
      float rstd = rsqrtf(var + 1e-5f);
      float4 oA, oB;
      oA.x = (ww[st][0] - mu) * rstd * gA.x + cAv.x;
      oA.y = (ww[st][1] - mu) * rstd * gA.y + cAv.y;
      oA.z = (ww[st][2] - mu) * rstd * gA.z + cAv.z;
      oA.w = (ww[st][3] - mu) * rstd * gA.w + cAv.w;
      oB.x = (ww[st][4] - mu) * rstd * gB.x + cBv.x;
      oB.y = (ww[st][5] - mu) * rstd * gB.y + cBv.y;
      oB.z = (ww[st][6] - mu) * rstd * gB.z + cBv.z;
      oB.w = (ww[st][7] - mu) * rstd * gB.w + cBv.w;
      float* orow = outp + (size_t)(tb + st * 16 + fr) * 128;
      *reinterpret_cast<float4*>(orow + cA) = oA;
      *reinterpret_cast<float4*>(orow + cB) = oB;
    }
  }
}

extern "C" void kernel_launch(void* const* d_in, const int* in_sizes, int n_in,
                              void* d_out, int out_size, void* d_ws, size_t ws_size,
                              hipStream_t stream) {
  const float* xq = (const float*)d_in[0];
  const float* kv = (const float*)d_in[1];
  const float* wkv = (const float*)d_in[2];
  const float* wq = (const float*)d_in[3];
  const float* wmh = (const float*)d_in[4];
  const float* bmh = (const float*)d_in[5];
  const float* w1 = (const float*)d_in[6];
  const float* b1 = (const float*)d_in[7];
  const float* w2 = (const float*)d_in[8];
  const float* b2 = (const float*)d_in[9];
  const float* g1 = (const float*)d_in[10];
  const float* bb1 = (const float*)d_in[11];
  const float* g2 = (const float*)d_in[12];
  const float* bb2 = (const float*)d_in[13];
  __half* ws = (__half*)d_ws;

  prep_weights<<<(WS_HALVES + 255) / 256, 256, 0, stream>>>(wq, wkv, wmh, w1, w2, ws);

  const int tokens = 32768;
  ca_mfma<<<tokens / TB, 256, 0, stream>>>(xq, kv, ws, bmh, b1, b2,
                                           g1, bb1, g2, bb2, (float*)d_out);
}